// Round 24
// baseline (1769.872 us; speedup 1.0000x reference)
//
#include <hip/hip_runtime.h>
#include <hip/hip_bf16.h>

#define KC 256
#define DIM 64
#define NITER 10
#define CPAD 66    // c_lds row stride in shorts: 33 words = 1 mod 32 -> spread banks
#define SUMBR 128  // sum4 rows per batch

typedef __attribute__((ext_vector_type(16))) float f32x16;
typedef __attribute__((ext_vector_type(4)))  float f32x4;
typedef __attribute__((ext_vector_type(8)))  short bf16x8;
typedef __attribute__((address_space(3))) const float lds_cf;

// numpy pairwise sum for 64 elements, inputs already rounded f32:
// r[j] = a[j]+a[j+8]+...+a[j+56] (sequential), then ((r0+r1)+(r2+r3))+((r4+r5)+(r6+r7))
__device__ __forceinline__ float np_pairwise_sq64(const float* a) {
    float r[8];
#pragma unroll
    for (int j = 0; j < 8; ++j) r[j] = __fmul_rn(a[j], a[j]);
#pragma unroll
    for (int i = 8; i < 64; i += 8)
#pragma unroll
        for (int j = 0; j < 8; ++j)
            r[j] = __fadd_rn(r[j], __fmul_rn(a[i + j], a[i + j]));
    float t01 = __fadd_rn(r[0], r[1]), t23 = __fadd_rn(r[2], r[3]);
    float t45 = __fadd_rn(r[4], r[5]), t67 = __fadd_rn(r[6], r[7]);
    return __fadd_rn(__fadd_rn(t01, t23), __fadd_rn(t45, t67));
}

__device__ __forceinline__ unsigned short f2bf(float f) {
    __hip_bfloat16 h = __float2bfloat16(f);   // RNE
    return *reinterpret_cast<unsigned short*>(&h);
}

// ---------------- init: c = x[:K] ----------------
__global__ void init_k(const float* __restrict__ x, float* __restrict__ c) {
    const int idx = blockIdx.x * 256 + threadIdx.x;
    if (idx < KC * DIM) c[idx] = x[idx];
}

// ---------------- xinit: once — x_bf16 + exact xsq per point ----------------
__global__ __launch_bounds__(256) void xinit_k(
    const float* __restrict__ x, unsigned short* __restrict__ xbf,
    float* __restrict__ xsq_g, int n)
{
    const int i = blockIdx.x * 256 + threadIdx.x;
    if (i >= n) return;
    float xr[DIM];
    const float4* xv = reinterpret_cast<const float4*>(x + (size_t)i * DIM);
    unsigned short* xb = xbf + (size_t)i * DIM;
#pragma unroll
    for (int j = 0; j < DIM / 4; ++j) {
        float4 v = xv[j];
        xr[4 * j + 0] = v.x; xr[4 * j + 1] = v.y;
        xr[4 * j + 2] = v.z; xr[4 * j + 3] = v.w;
        xb[4 * j + 0] = f2bf(v.x); xb[4 * j + 1] = f2bf(v.y);
        xb[4 * j + 2] = f2bf(v.z); xb[4 * j + 3] = f2bf(v.w);
    }
    xsq_g[i] = np_pairwise_sq64(xr);
}

// ---------------- csqg: per-iter csq, firstNaN (non-mfma path) ----------------
__global__ __launch_bounds__(256) void csqg_k(
    const float* __restrict__ c, float* __restrict__ csq_g, int* __restrict__ nan_g)
{
    const int k = threadIdx.x;
    if (k == 0) *nan_g = 0x7fffffff;
    __syncthreads();
    float cr[DIM];
    const float4* cp = reinterpret_cast<const float4*>(c + k * DIM);
#pragma unroll
    for (int j = 0; j < DIM / 4; ++j) {
        float4 v = cp[j];
        cr[4 * j + 0] = v.x; cr[4 * j + 1] = v.y;
        cr[4 * j + 2] = v.z; cr[4 * j + 3] = v.w;
    }
    const float s = np_pairwise_sq64(cr);
    csq_g[k] = s;
    if (s != s) atomicMin(nan_g, k);
}

// ---------------- csqg2: per-iter csq + firstNaN + c_bf16 + csqmax (mfma path) ----------------
__global__ __launch_bounds__(256) void csqg2_k(
    const float* __restrict__ c, float* __restrict__ csq_g, int* __restrict__ nan_g,
    unsigned short* __restrict__ cbf, float* __restrict__ csqmax_g)
{
    __shared__ float smax[256];
    const int k = threadIdx.x;
    if (k == 0) *nan_g = 0x7fffffff;
    __syncthreads();
    float cr[DIM];
    const float4* cp = reinterpret_cast<const float4*>(c + k * DIM);
    unsigned short* cb = cbf + (size_t)k * DIM;
#pragma unroll
    for (int j = 0; j < DIM / 4; ++j) {
        float4 v = cp[j];
        cr[4 * j + 0] = v.x; cr[4 * j + 1] = v.y;
        cr[4 * j + 2] = v.z; cr[4 * j + 3] = v.w;
        cb[4 * j + 0] = f2bf(v.x); cb[4 * j + 1] = f2bf(v.y);
        cb[4 * j + 2] = f2bf(v.z); cb[4 * j + 3] = f2bf(v.w);
    }
    const float s = np_pairwise_sq64(cr);
    csq_g[k] = s;
    if (s != s) atomicMin(nan_g, k);
    smax[k] = (s == s) ? s : 0.0f;
    __syncthreads();
    for (int d = 128; d >= 1; d >>= 1) {
        if (k < d) smax[k] = fmaxf(smax[k], smax[k + d]);
        __syncthreads();
    }
    if (k == 0) *csqmax_g = smax[0];
}

// ---------------- assign: two-pass MFMA screen, c staged in 128-cluster halves (r21-proven) ----------------
__global__ __launch_bounds__(256) void assign_mfma_k(
    const float* __restrict__ x, const unsigned short* __restrict__ xbf,
    const float* __restrict__ xsq_g, const float* __restrict__ c,
    const unsigned short* __restrict__ cbf, const float* __restrict__ csq_g,
    const float* __restrict__ csqmax_g, const int* __restrict__ nan_g,
    float* __restrict__ labels, int* __restrict__ hist, int n)
{
    __shared__ unsigned short c_lds[128 * CPAD];  // 16896 B (one half of clusters)
    __shared__ float csq_lds[KC];                 // 1024 B
    __shared__ int u_shm[1024];                   // 4096 B: cand -> whist
    __shared__ int ccnt[256];                     // 1024 B

    short* cand = reinterpret_cast<short*>(u_shm);
    const int t = threadIdx.x;
    const int p0 = blockIdx.x * 256;

    csq_lds[t] = csq_g[t];
    ccnt[t] = 0;
    const float csqmax = *csqmax_g;
    const int firstNan = *nan_g;

    const int w = t >> 6, l = t & 63;
    const int grp = l >> 4, lr = l & 15;

    float rm[4][4];
#pragma unroll
    for (int q = 0; q < 4; ++q)
#pragma unroll
        for (int p = 0; p < 4; ++p) rm[q][p] = 3.4e38f;

    // ---- pass A: running min over both halves ----
#pragma unroll
    for (int h = 0; h < 2; ++h) {
        __syncthreads();
        for (int idx = t; idx < 128 * 8; idx += 256) {
            const int row = idx >> 3, ch = idx & 7;
            *reinterpret_cast<bf16x8*>(&c_lds[row * CPAD + ch * 8]) =
                *reinterpret_cast<const bf16x8*>(cbf + (size_t)(h * 128 + row) * DIM + ch * 8);
        }
        __syncthreads();
#pragma unroll
        for (int q = 0; q < 4; ++q) {
            const int pbase = p0 + w * 64 + q * 16;
            const unsigned short* xb = xbf + (size_t)(pbase + lr) * DIM;
            const bf16x8 a0 = *reinterpret_cast<const bf16x8*>(xb + grp * 8);
            const bf16x8 a1 = *reinterpret_cast<const bf16x8*>(xb + 32 + grp * 8);
            const int prow = pbase + grp * 4;
            const float xs0 = xsq_g[prow + 0], xs1 = xsq_g[prow + 1];
            const float xs2 = xsq_g[prow + 2], xs3 = xsq_g[prow + 3];
#pragma unroll
            for (int ct = 0; ct < 8; ++ct) {
                const unsigned short* cb = &c_lds[(ct * 16 + lr) * CPAD];
                const bf16x8 b0 = *reinterpret_cast<const bf16x8*>(cb + grp * 8);
                const bf16x8 b1 = *reinterpret_cast<const bf16x8*>(cb + 32 + grp * 8);
                f32x4 acc = {0.f, 0.f, 0.f, 0.f};
                acc = __builtin_amdgcn_mfma_f32_16x16x32_bf16(a0, b0, acc, 0, 0, 0);
                acc = __builtin_amdgcn_mfma_f32_16x16x32_bf16(a1, b1, acc, 0, 0, 0);
                const float cs = csq_lds[h * 128 + ct * 16 + lr];
                rm[q][0] = fminf(rm[q][0], __fadd_rn(fmaf(-2.0f, acc[0], xs0), cs));
                rm[q][1] = fminf(rm[q][1], __fadd_rn(fmaf(-2.0f, acc[1], xs1), cs));
                rm[q][2] = fminf(rm[q][2], __fadd_rn(fmaf(-2.0f, acc[2], xs2), cs));
                rm[q][3] = fminf(rm[q][3], __fadd_rn(fmaf(-2.0f, acc[3], xs3), cs));
            }
        }
    }

    // ---- reduce rm across the 16-lane groups ----
#pragma unroll
    for (int q = 0; q < 4; ++q) {
#pragma unroll
        for (int m = 1; m < 16; m <<= 1) {
            rm[q][0] = fminf(rm[q][0], __shfl_xor(rm[q][0], m, 64));
            rm[q][1] = fminf(rm[q][1], __shfl_xor(rm[q][1], m, 64));
            rm[q][2] = fminf(rm[q][2], __shfl_xor(rm[q][2], m, 64));
            rm[q][3] = fminf(rm[q][3], __shfl_xor(rm[q][3], m, 64));
        }
    }

    // ---- pass B: recompute (bitwise-identical) + push candidates ----
#pragma unroll
    for (int h = 0; h < 2; ++h) {
        __syncthreads();
        for (int idx = t; idx < 128 * 8; idx += 256) {
            const int row = idx >> 3, ch = idx & 7;
            *reinterpret_cast<bf16x8*>(&c_lds[row * CPAD + ch * 8]) =
                *reinterpret_cast<const bf16x8*>(cbf + (size_t)(h * 128 + row) * DIM + ch * 8);
        }
        __syncthreads();
#pragma unroll
        for (int q = 0; q < 4; ++q) {
            const int pbase = p0 + w * 64 + q * 16;
            const unsigned short* xb = xbf + (size_t)(pbase + lr) * DIM;
            const bf16x8 a0 = *reinterpret_cast<const bf16x8*>(xb + grp * 8);
            const bf16x8 a1 = *reinterpret_cast<const bf16x8*>(xb + 32 + grp * 8);
            const int prow = pbase + grp * 4;
            const float xs0 = xsq_g[prow + 0], xs1 = xsq_g[prow + 1];
            const float xs2 = xsq_g[prow + 2], xs3 = xsq_g[prow + 3];
            const float th0 = rm[q][0] + 2.0f * (0.00399f * sqrtf(xs0 * csqmax) + 0.02f);
            const float th1 = rm[q][1] + 2.0f * (0.00399f * sqrtf(xs1 * csqmax) + 0.02f);
            const float th2 = rm[q][2] + 2.0f * (0.00399f * sqrtf(xs2 * csqmax) + 0.02f);
            const float th3 = rm[q][3] + 2.0f * (0.00399f * sqrtf(xs3 * csqmax) + 0.02f);
            const int pidx0 = w * 64 + q * 16 + grp * 4;
#pragma unroll
            for (int ct = 0; ct < 8; ++ct) {
                const unsigned short* cb = &c_lds[(ct * 16 + lr) * CPAD];
                const bf16x8 b0 = *reinterpret_cast<const bf16x8*>(cb + grp * 8);
                const bf16x8 b1 = *reinterpret_cast<const bf16x8*>(cb + 32 + grp * 8);
                f32x4 acc = {0.f, 0.f, 0.f, 0.f};
                acc = __builtin_amdgcn_mfma_f32_16x16x32_bf16(a0, b0, acc, 0, 0, 0);
                acc = __builtin_amdgcn_mfma_f32_16x16x32_bf16(a1, b1, acc, 0, 0, 0);
                const int kcol = h * 128 + ct * 16 + lr;
                const float cs = csq_lds[kcol];
                const float d0 = __fadd_rn(fmaf(-2.0f, acc[0], xs0), cs);
                const float d1 = __fadd_rn(fmaf(-2.0f, acc[1], xs1), cs);
                const float d2 = __fadd_rn(fmaf(-2.0f, acc[2], xs2), cs);
                const float d3 = __fadd_rn(fmaf(-2.0f, acc[3], xs3), cs);
                if (d0 <= th0) { int s = atomicAdd(&ccnt[pidx0 + 0], 1); if (s < 8) cand[(pidx0 + 0) * 8 + s] = (short)kcol; }
                if (d1 <= th1) { int s = atomicAdd(&ccnt[pidx0 + 1], 1); if (s < 8) cand[(pidx0 + 1) * 8 + s] = (short)kcol; }
                if (d2 <= th2) { int s = atomicAdd(&ccnt[pidx0 + 2], 1); if (s < 8) cand[(pidx0 + 2) * 8 + s] = (short)kcol; }
                if (d3 <= th3) { int s = atomicAdd(&ccnt[pidx0 + 3], 1); if (s < 8) cand[(pidx0 + 3) * 8 + s] = (short)kcol; }
            }
        }
    }
    __syncthreads();

    // ---- eval: nc==1 -> candidate IS the exact argmin; else exact r4 chain ----
    const int i = p0 + t;
    const bool valid = (i < n);
    int lbl = 0;
    if (valid) {
        const int nc = ccnt[t];
        if (firstNan != 0x7fffffff) {
            lbl = firstNan;
        } else if (nc == 1) {
            lbl = (int)cand[t * 8];
        } else {
            const float xsqv = xsq_g[i];
            const float4* xrow = reinterpret_cast<const float4*>(x + (size_t)i * DIM);
            float bd = 3.4e38f;
            int bk = 0;
            const bool fullscan = (nc == 0) || (nc > 8);
            const int lim = fullscan ? KC : nc;
            for (int s = 0; s < lim; ++s) {
                const int k = fullscan ? s : (int)cand[t * 8 + s];
                const float4* crow = reinterpret_cast<const float4*>(c + (size_t)k * DIM);
                float acc = 0.0f;
#pragma unroll
                for (int db = 0; db < 16; ++db) {
                    const float4 a = xrow[db], b = crow[db];
                    acc = fmaf(a.x, b.x, acc); acc = fmaf(a.y, b.y, acc);
                    acc = fmaf(a.z, b.z, acc); acc = fmaf(a.w, b.w, acc);
                }
                const float dd = __fadd_rn(fmaf(-2.0f, acc, xsqv), csq_lds[k]);
                if (dd < bd) { bd = dd; bk = k; }
                else if (dd == bd && k < bk) bk = k;
            }
            lbl = bk;
        }
        labels[i] = (float)lbl;
    }
    __syncthreads();                 // all cand/ccnt reads done -> safe to reuse u_shm

    // ---- whist ballot (u_shm reused) ----
    int* whist = u_shm;
    for (int j = t; j < 4 * KC; j += 256) whist[j] = 0;
    __syncthreads();
    const int lane = t & 63, wv = t >> 6;
    unsigned long long same = __ballot(valid);
#pragma unroll
    for (int bit = 0; bit < 8; ++bit) {
        unsigned long long bb = __ballot((lbl >> bit) & 1);
        same &= ((lbl >> bit) & 1) ? bb : ~bb;
    }
    if (valid && lane == __builtin_ctzll(same))
        whist[wv * KC + lbl] = (int)__popcll(same);
    __syncthreads();
    if (t < KC)
        hist[(size_t)blockIdx.x * KC + t] =
            whist[t] + whist[KC + t] + whist[2 * KC + t] + whist[3 * KC + t];
}

// ---------------- fallback assign (r15-proven, passing) ----------------
__global__ __launch_bounds__(256) void assign_hist_k(
    const float* __restrict__ x, const float* __restrict__ c,
    const float* __restrict__ csq_g, const int* __restrict__ nan_g,
    float* __restrict__ labels, int* __restrict__ hist, int n)
{
    __shared__ int whist[4 * KC];
    const int t = threadIdx.x;
    for (int j = t; j < 4 * KC; j += 256) whist[j] = 0;

    const int i = blockIdx.x * 256 + t;
    const bool valid = (i < n);

    float xr[DIM];
    const float4* xv = reinterpret_cast<const float4*>(x + (size_t)(valid ? i : 0) * DIM);
#pragma unroll
    for (int j = 0; j < DIM / 4; ++j) {
        float4 v = xv[j];
        xr[4 * j + 0] = v.x; xr[4 * j + 1] = v.y;
        xr[4 * j + 2] = v.z; xr[4 * j + 3] = v.w;
    }
    const float xsq = np_pairwise_sq64(xr);
    const int firstNan = *nan_g;

    float best = __int_as_float(0x7f800000);
    int bk = 0;

#pragma unroll 1
    for (int k = 0; k < KC; ++k) {
        f32x16 h0, h1, h2, h3;
        float cs;
        const float* rp = c + (size_t)k * DIM;
        asm volatile("s_load_dwordx16 %0, %1, 0x0"  : "=s"(h0) : "s"(rp));
        asm volatile("s_load_dwordx16 %0, %1, 0x40" : "=s"(h1) : "s"(rp));
        asm volatile("s_load_dwordx16 %0, %1, 0x80" : "=s"(h2) : "s"(rp));
        asm volatile("s_load_dwordx16 %0, %1, 0xc0" : "=s"(h3) : "s"(rp));
        asm volatile("s_load_dword %0, %1, 0x0"     : "=s"(cs) : "s"(csq_g + k));
        asm volatile("s_waitcnt lgkmcnt(0)"
                     : "+s"(h0), "+s"(h1), "+s"(h2), "+s"(h3), "+s"(cs));
        __builtin_amdgcn_sched_barrier(0);

        float acc = 0.0f;
#pragma unroll
        for (int d = 0; d < 16; ++d) acc = fmaf(xr[d],      h0[d], acc);
#pragma unroll
        for (int d = 0; d < 16; ++d) acc = fmaf(xr[16 + d], h1[d], acc);
#pragma unroll
        for (int d = 0; d < 16; ++d) acc = fmaf(xr[32 + d], h2[d], acc);
#pragma unroll
        for (int d = 0; d < 16; ++d) acc = fmaf(xr[48 + d], h3[d], acc);

        const float dist = __fadd_rn(fmaf(-2.0f, acc, xsq), cs);
        if (dist < best) { best = dist; bk = k; }
    }

    int lbl = 0;
    if (valid) {
        lbl = (firstNan != 0x7fffffff) ? firstNan : bk;
        labels[i] = (float)lbl;
    }

    __syncthreads();
    const int lane = t & 63, w = t >> 6;
    unsigned long long same = __ballot(valid);
#pragma unroll
    for (int bit = 0; bit < 8; ++bit) {
        unsigned long long bb = __ballot((lbl >> bit) & 1);
        same &= ((lbl >> bit) & 1) ? bb : ~bb;
    }
    if (valid && lane == __builtin_ctzll(same))
        whist[w * KC + lbl] = (int)__popcll(same);
    __syncthreads();
    if (t < KC)
        hist[(size_t)blockIdx.x * KC + t] =
            whist[t] + whist[KC + t] + whist[2 * KC + t] + whist[3 * KC + t];
}

// ---------------- scan1: per-cluster exclusive prefix over blocks ----------------
__global__ __launch_bounds__(256) void scan1_k(
    int* __restrict__ hist, int nb, int* __restrict__ cnt)
{
    __shared__ int sbuf[256];
    const int k = blockIdx.x;
    const int t = threadIdx.x;
    const int epb = (nb + 255) / 256;
    const int b0 = t * epb;

    int s = 0;
    for (int u = 0; u < epb; ++u) {
        const int b = b0 + u;
        if (b < nb) s += hist[(size_t)b * KC + k];
    }
    sbuf[t] = s;
    __syncthreads();
    int incl = s;
#pragma unroll
    for (int d = 1; d < 256; d <<= 1) {
        const int v = (t >= d) ? sbuf[t - d] : 0;
        __syncthreads();
        incl += v;
        sbuf[t] = incl;
        __syncthreads();
    }
    int run = incl - s;
    for (int u = 0; u < epb; ++u) {
        const int b = b0 + u;
        if (b < nb) {
            const int v = hist[(size_t)b * KC + k];
            hist[(size_t)b * KC + k] = run;
            run += v;
        }
    }
    if (t == 255) cnt[k] = incl;
}

// ---------------- scan2: cluster bases (padded to 64 rows) ----------------
__global__ __launch_bounds__(256) void scan2_k(
    const int* __restrict__ cnt, int* __restrict__ base)
{
    __shared__ int sbuf[256];
    const int t = threadIdx.x;
    const int padded = (cnt[t] + 63) & ~63;
    sbuf[t] = padded;
    __syncthreads();
    int incl = padded;
#pragma unroll
    for (int d = 1; d < 256; d <<= 1) {
        const int v = (t >= d) ? sbuf[t - d] : 0;
        __syncthreads();
        incl += v;
        sbuf[t] = incl;
        __syncthreads();
    }
    base[t] = incl - padded;
}

// ---------------- scatter: stable counting-sort placement ----------------
__global__ __launch_bounds__(256) void scatter_k(
    const float* __restrict__ labels, const int* __restrict__ hist,
    const int* __restrict__ base, int* __restrict__ order, int n)
{
    __shared__ int whist[4 * KC];
    const int t = threadIdx.x;
    for (int j = t; j < 4 * KC; j += 256) whist[j] = 0;
    __syncthreads();

    const int i = blockIdx.x * 256 + t;
    const bool valid = (i < n);
    const int lbl = valid ? (int)labels[i] : 0;
    const int lane = t & 63, w = t >> 6;

    unsigned long long same = __ballot(valid);
#pragma unroll
    for (int bit = 0; bit < 8; ++bit) {
        unsigned long long bb = __ballot((lbl >> bit) & 1);
        same &= ((lbl >> bit) & 1) ? bb : ~bb;
    }
    const unsigned long long below = (1ull << lane) - 1ull;
    const int rank_wave = (int)__popcll(same & below);
    if (valid && lane == __builtin_ctzll(same))
        whist[w * KC + lbl] = (int)__popcll(same);
    __syncthreads();

    if (valid) {
        int off = rank_wave;
        for (int ww = 0; ww < w; ++ww) off += whist[ww * KC + lbl];
        const int pos = base[lbl] + hist[(size_t)blockIdx.x * KC + lbl] + off;
        order[pos] = i;
    }
}

// ---------------- permute: xs[pos][d] = x[order[pos]][d]; pads (order<0) -> zero rows ----------------
__global__ __launch_bounds__(256) void permute_k(
    const float* __restrict__ x, const int* __restrict__ order,
    float* __restrict__ xs)
{
    const int r = blockIdx.x * 4 + (threadIdx.x >> 6);   // row (sorted position)
    const int d = threadIdx.x & 63;
    const int idx = order[r];                            // wave-uniform
    float v = 0.0f;
    if (idx >= 0) v = x[(size_t)idx * DIM + d];          // coalesced 256B row read
    xs[(size_t)r * DIM + d] = v;                         // coalesced 256B row write
}

// ---------------- sum4: producer/consumer; consumer hand-pipelined via asm ds_read ----------------
// One block per cluster, 512 threads. Waves 0-6 stream 128-row batches to a double-
// buffered LDS; wave 7 chains from LDS with 16 ds_read_b32 in flight per step.
// Values and ascending order identical to the proven sum2; pads exact +0.0 no-ops.
__global__ __launch_bounds__(512) void sum4_k(
    const float* __restrict__ xs, const int* __restrict__ base,
    const int* __restrict__ cnt, float* __restrict__ c)
{
    __shared__ float sbuf[2][SUMBR * DIM];    // 2 x 32 KiB

    const int k = blockIdx.x;
    const int t = threadIdx.x;
    const int w = t >> 6;
    const int lane = t & 63;
    const int b0 = base[k];                   // multiple of 64
    const int ct = cnt[k];
    const int ctp = (ct + 63) & ~63;          // padded rows (zero rows at tail)
    const int nbt = (ctp + SUMBR - 1) / SUMBR;

    const f32x4* src4 = reinterpret_cast<const f32x4*>(xs + (size_t)b0 * DIM);

    // preload batch 0 (waves 0-6)
    if (w < 7 && nbt > 0) {
        const int bs4 = ((ctp < SUMBR) ? ctp : SUMBR) * 16;   // float4 count
        f32x4* dst4 = reinterpret_cast<f32x4*>(sbuf[0]);
        for (int idx = t; idx < bs4; idx += 448)
            dst4[idx] = src4[idx];
    }
    __syncthreads();

    float acc = 0.0f;
    for (int b = 0; b < nbt; ++b) {
        if (w < 7) {
            // producers: load batch b+1 into the other buffer
            if (b + 1 < nbt) {
                const int jb = (b + 1) * SUMBR;
                const int rows = ((ctp - jb) < SUMBR) ? (ctp - jb) : SUMBR;
                const int bs4 = rows * 16;
                f32x4* dst4 = reinterpret_cast<f32x4*>(sbuf[(b + 1) & 1]);
                for (int idx = t; idx < bs4; idx += 448)
                    dst4[idx] = src4[(size_t)jb * 16 + idx];
            }
        } else {
            // consumer: exact ascending chain, 16 rows per asm block (rows % 16 == 0)
            const int jb = b * SUMBR;
            const int rows = ((ctp - jb) < SUMBR) ? (ctp - jb) : SUMBR;
            unsigned a = (unsigned)(uintptr_t)(lds_cf*)&sbuf[b & 1][lane];
            const int nblk = rows >> 4;
            for (int blk = 0; blk < nblk; ++blk) {
                float t0, t1, t2, t3, t4, t5, t6, t7;
                float t8, t9, t10, t11, t12, t13, t14, t15;
                asm volatile(
                    "ds_read_b32 %0, %16 offset:0\n\t"
                    "ds_read_b32 %1, %16 offset:256\n\t"
                    "ds_read_b32 %2, %16 offset:512\n\t"
                    "ds_read_b32 %3, %16 offset:768\n\t"
                    "ds_read_b32 %4, %16 offset:1024\n\t"
                    "ds_read_b32 %5, %16 offset:1280\n\t"
                    "ds_read_b32 %6, %16 offset:1536\n\t"
                    "ds_read_b32 %7, %16 offset:1792\n\t"
                    "ds_read_b32 %8, %16 offset:2048\n\t"
                    "ds_read_b32 %9, %16 offset:2304\n\t"
                    "ds_read_b32 %10, %16 offset:2560\n\t"
                    "ds_read_b32 %11, %16 offset:2816\n\t"
                    "ds_read_b32 %12, %16 offset:3072\n\t"
                    "ds_read_b32 %13, %16 offset:3328\n\t"
                    "ds_read_b32 %14, %16 offset:3584\n\t"
                    "ds_read_b32 %15, %16 offset:3840\n\t"
                    "s_waitcnt lgkmcnt(0)"
                    : "=v"(t0), "=v"(t1), "=v"(t2), "=v"(t3),
                      "=v"(t4), "=v"(t5), "=v"(t6), "=v"(t7),
                      "=v"(t8), "=v"(t9), "=v"(t10), "=v"(t11),
                      "=v"(t12), "=v"(t13), "=v"(t14), "=v"(t15)
                    : "v"(a));
                __builtin_amdgcn_sched_barrier(0);
                acc = __fadd_rn(acc, t0);  acc = __fadd_rn(acc, t1);
                acc = __fadd_rn(acc, t2);  acc = __fadd_rn(acc, t3);
                acc = __fadd_rn(acc, t4);  acc = __fadd_rn(acc, t5);
                acc = __fadd_rn(acc, t6);  acc = __fadd_rn(acc, t7);
                acc = __fadd_rn(acc, t8);  acc = __fadd_rn(acc, t9);
                acc = __fadd_rn(acc, t10); acc = __fadd_rn(acc, t11);
                acc = __fadd_rn(acc, t12); acc = __fadd_rn(acc, t13);
                acc = __fadd_rn(acc, t14); acc = __fadd_rn(acc, t15);
                a += 4096;   // 16 rows * 256 B
            }
        }
        __syncthreads();
    }

    if (w == 7)
        c[k * DIM + lane] = __fdiv_rn(acc, (float)ct);   // 0/0 -> NaN matches ref
}

// ---------------- fallback gather (used only if d_ws too small) ----------------
__global__ __launch_bounds__(64) void gather_k(
    const float* __restrict__ x, const int* __restrict__ order,
    const int* __restrict__ base, const int* __restrict__ cnt,
    float* __restrict__ c)
{
    const int k = blockIdx.x;
    const int lane = threadIdx.x;
    const int b0 = base[k];
    const int ct = cnt[k];
    float acc = 0.0f;
    int j = 0;
    for (; j + 32 <= ct; j += 32) {
        float v[32];
#pragma unroll
        for (int u = 0; u < 32; ++u)
            v[u] = x[(size_t)order[b0 + j + u] * DIM + lane];
#pragma unroll
        for (int u = 0; u < 32; ++u) acc = __fadd_rn(acc, v[u]);
    }
    for (; j < ct; ++j)
        acc = __fadd_rn(acc, x[(size_t)order[b0 + j] * DIM + lane]);
    c[k * DIM + lane] = __fdiv_rn(acc, (float)ct);
}

extern "C" void kernel_launch(void* const* d_in, const int* in_sizes, int n_in,
                              void* d_out, int out_size, void* d_ws, size_t ws_size,
                              hipStream_t stream)
{
    const float* x = (const float*)d_in[0];
    const int n = in_sizes[0] / DIM;          // 262144

    float* out_c = (float*)d_out;
    float* out_labels = out_c + KC * DIM;

    const int nb = (n + 255) / 256;           // 1024 blocks of 256 points
    const int nstride = n + KC * 64;          // padded sorted-position capacity

    size_t off = 0;
    auto alloc = [&](size_t bytes) -> size_t {
        size_t o = off; off = (off + bytes + 255) & ~(size_t)255; return o;
    };
    char*  w        = (char*)d_ws;
    float* csq_g    = (float*)(w + alloc(KC * sizeof(float)));
    int*   nan_g    = (int*)(w + alloc(256));
    float* csqmax_g = (float*)(w + alloc(256));
    unsigned short* cbf_g = (unsigned short*)(w + alloc(KC * DIM * sizeof(unsigned short)));
    int*   hist  = (int*)(w + alloc((size_t)nb * KC * sizeof(int)));
    int*   base  = (int*)(w + alloc(KC * sizeof(int)));
    int*   cnt   = (int*)(w + alloc(KC * sizeof(int)));
    int*   order = (int*)(w + alloc((size_t)nstride * sizeof(int)));
    const size_t med_need = off;
    float* xs    = (float*)(w + alloc((size_t)nstride * DIM * sizeof(float)));
    const size_t big_need = off;
    unsigned short* xbf = (unsigned short*)(w + alloc((size_t)n * DIM * sizeof(unsigned short)));
    float* xsq_g = (float*)(w + alloc((size_t)n * sizeof(float)));
    const size_t huge_need = off;

    const bool med  = (ws_size >= med_need);
    const bool big  = (ws_size >= big_need);
    const bool huge = (ws_size >= huge_need);

    init_k<<<(KC * DIM + 255) / 256, 256, 0, stream>>>(x, out_c);
    if (huge)
        xinit_k<<<nb, 256, 0, stream>>>(x, xbf, xsq_g, n);

    for (int it = 0; it < NITER; ++it) {
        if (huge) {
            csqg2_k<<<1, 256, 0, stream>>>(out_c, csq_g, nan_g, cbf_g, csqmax_g);
            assign_mfma_k<<<nb, 256, 0, stream>>>(x, xbf, xsq_g, out_c, cbf_g,
                                                  csq_g, csqmax_g, nan_g,
                                                  out_labels, hist, n);
        } else {
            csqg_k<<<1, 256, 0, stream>>>(out_c, csq_g, nan_g);
            assign_hist_k<<<nb, 256, 0, stream>>>(x, out_c, csq_g, nan_g,
                                                  out_labels, hist, n);
        }
        if (med) {
            scan1_k<<<KC, 256, 0, stream>>>(hist, nb, cnt);
            scan2_k<<<1, 256, 0, stream>>>(cnt, base);
            if (big) {
                (void)hipMemsetAsync(order, 0xFF, (size_t)nstride * sizeof(int), stream);
                scatter_k<<<nb, 256, 0, stream>>>(out_labels, hist, base, order, n);
                permute_k<<<nstride / 4, 256, 0, stream>>>(x, order, xs);
                sum4_k<<<KC, 512, 0, stream>>>(xs, base, cnt, out_c);
            } else {
                scatter_k<<<nb, 256, 0, stream>>>(out_labels, hist, base, order, n);
                gather_k<<<KC, 64, 0, stream>>>(x, order, base, cnt, out_c);
            }
        }
    }
}

// Round 25
// 1446.657 us; speedup vs baseline: 1.2234x; 1.2234x over previous
//
#include <hip/hip_runtime.h>
#include <hip/hip_bf16.h>

#define KC 256
#define DIM 64
#define NITER 10
#define CPAD 66    // c_lds row stride in shorts: 33 words = 1 mod 32 -> spread banks

typedef __attribute__((ext_vector_type(16))) float f32x16;
typedef __attribute__((ext_vector_type(4)))  float f32x4;
typedef __attribute__((ext_vector_type(8)))  short bf16x8;

// numpy pairwise sum for 64 elements, inputs already rounded f32:
// r[j] = a[j]+a[j+8]+...+a[j+56] (sequential), then ((r0+r1)+(r2+r3))+((r4+r5)+(r6+r7))
__device__ __forceinline__ float np_pairwise_sq64(const float* a) {
    float r[8];
#pragma unroll
    for (int j = 0; j < 8; ++j) r[j] = __fmul_rn(a[j], a[j]);
#pragma unroll
    for (int i = 8; i < 64; i += 8)
#pragma unroll
        for (int j = 0; j < 8; ++j)
            r[j] = __fadd_rn(r[j], __fmul_rn(a[i + j], a[i + j]));
    float t01 = __fadd_rn(r[0], r[1]), t23 = __fadd_rn(r[2], r[3]);
    float t45 = __fadd_rn(r[4], r[5]), t67 = __fadd_rn(r[6], r[7]);
    return __fadd_rn(__fadd_rn(t01, t23), __fadd_rn(t45, t67));
}

__device__ __forceinline__ unsigned short f2bf(float f) {
    __hip_bfloat16 h = __float2bfloat16(f);   // RNE
    return *reinterpret_cast<unsigned short*>(&h);
}

// ---------------- init: c = x[:K] ----------------
__global__ void init_k(const float* __restrict__ x, float* __restrict__ c) {
    const int idx = blockIdx.x * 256 + threadIdx.x;
    if (idx < KC * DIM) c[idx] = x[idx];
}

// ---------------- xinit: once — x_bf16 + exact xsq per point ----------------
__global__ __launch_bounds__(256) void xinit_k(
    const float* __restrict__ x, unsigned short* __restrict__ xbf,
    float* __restrict__ xsq_g, int n)
{
    const int i = blockIdx.x * 256 + threadIdx.x;
    if (i >= n) return;
    float xr[DIM];
    const float4* xv = reinterpret_cast<const float4*>(x + (size_t)i * DIM);
    unsigned short* xb = xbf + (size_t)i * DIM;
#pragma unroll
    for (int j = 0; j < DIM / 4; ++j) {
        float4 v = xv[j];
        xr[4 * j + 0] = v.x; xr[4 * j + 1] = v.y;
        xr[4 * j + 2] = v.z; xr[4 * j + 3] = v.w;
        xb[4 * j + 0] = f2bf(v.x); xb[4 * j + 1] = f2bf(v.y);
        xb[4 * j + 2] = f2bf(v.z); xb[4 * j + 3] = f2bf(v.w);
    }
    xsq_g[i] = np_pairwise_sq64(xr);
}

// ---------------- csqg: per-iter csq, firstNaN (non-mfma path) ----------------
__global__ __launch_bounds__(256) void csqg_k(
    const float* __restrict__ c, float* __restrict__ csq_g, int* __restrict__ nan_g)
{
    const int k = threadIdx.x;
    if (k == 0) *nan_g = 0x7fffffff;
    __syncthreads();
    float cr[DIM];
    const float4* cp = reinterpret_cast<const float4*>(c + k * DIM);
#pragma unroll
    for (int j = 0; j < DIM / 4; ++j) {
        float4 v = cp[j];
        cr[4 * j + 0] = v.x; cr[4 * j + 1] = v.y;
        cr[4 * j + 2] = v.z; cr[4 * j + 3] = v.w;
    }
    const float s = np_pairwise_sq64(cr);
    csq_g[k] = s;
    if (s != s) atomicMin(nan_g, k);
}

// ---------------- csqg2: per-iter csq + firstNaN + c_bf16 + csqmax (mfma path) ----------------
__global__ __launch_bounds__(256) void csqg2_k(
    const float* __restrict__ c, float* __restrict__ csq_g, int* __restrict__ nan_g,
    unsigned short* __restrict__ cbf, float* __restrict__ csqmax_g)
{
    __shared__ float smax[256];
    const int k = threadIdx.x;
    if (k == 0) *nan_g = 0x7fffffff;
    __syncthreads();
    float cr[DIM];
    const float4* cp = reinterpret_cast<const float4*>(c + k * DIM);
    unsigned short* cb = cbf + (size_t)k * DIM;
#pragma unroll
    for (int j = 0; j < DIM / 4; ++j) {
        float4 v = cp[j];
        cr[4 * j + 0] = v.x; cr[4 * j + 1] = v.y;
        cr[4 * j + 2] = v.z; cr[4 * j + 3] = v.w;
        cb[4 * j + 0] = f2bf(v.x); cb[4 * j + 1] = f2bf(v.y);
        cb[4 * j + 2] = f2bf(v.z); cb[4 * j + 3] = f2bf(v.w);
    }
    const float s = np_pairwise_sq64(cr);
    csq_g[k] = s;
    if (s != s) atomicMin(nan_g, k);
    smax[k] = (s == s) ? s : 0.0f;
    __syncthreads();
    for (int d = 128; d >= 1; d >>= 1) {
        if (k < d) smax[k] = fmaxf(smax[k], smax[k + d]);
        __syncthreads();
    }
    if (k == 0) *csqmax_g = smax[0];
}

// ---------------- assign: two-pass MFMA screen, c staged in 128-cluster halves (r21-proven) ----------------
__global__ __launch_bounds__(256) void assign_mfma_k(
    const float* __restrict__ x, const unsigned short* __restrict__ xbf,
    const float* __restrict__ xsq_g, const float* __restrict__ c,
    const unsigned short* __restrict__ cbf, const float* __restrict__ csq_g,
    const float* __restrict__ csqmax_g, const int* __restrict__ nan_g,
    float* __restrict__ labels, int* __restrict__ hist, int n)
{
    __shared__ unsigned short c_lds[128 * CPAD];  // 16896 B (one half of clusters)
    __shared__ float csq_lds[KC];                 // 1024 B
    __shared__ int u_shm[1024];                   // 4096 B: cand -> whist
    __shared__ int ccnt[256];                     // 1024 B

    short* cand = reinterpret_cast<short*>(u_shm);
    const int t = threadIdx.x;
    const int p0 = blockIdx.x * 256;

    csq_lds[t] = csq_g[t];
    ccnt[t] = 0;
    const float csqmax = *csqmax_g;
    const int firstNan = *nan_g;

    const int w = t >> 6, l = t & 63;
    const int grp = l >> 4, lr = l & 15;

    float rm[4][4];
#pragma unroll
    for (int q = 0; q < 4; ++q)
#pragma unroll
        for (int p = 0; p < 4; ++p) rm[q][p] = 3.4e38f;

    // ---- pass A: running min over both halves ----
#pragma unroll
    for (int h = 0; h < 2; ++h) {
        __syncthreads();
        for (int idx = t; idx < 128 * 8; idx += 256) {
            const int row = idx >> 3, ch = idx & 7;
            *reinterpret_cast<bf16x8*>(&c_lds[row * CPAD + ch * 8]) =
                *reinterpret_cast<const bf16x8*>(cbf + (size_t)(h * 128 + row) * DIM + ch * 8);
        }
        __syncthreads();
#pragma unroll
        for (int q = 0; q < 4; ++q) {
            const int pbase = p0 + w * 64 + q * 16;
            const unsigned short* xb = xbf + (size_t)(pbase + lr) * DIM;
            const bf16x8 a0 = *reinterpret_cast<const bf16x8*>(xb + grp * 8);
            const bf16x8 a1 = *reinterpret_cast<const bf16x8*>(xb + 32 + grp * 8);
            const int prow = pbase + grp * 4;
            const float xs0 = xsq_g[prow + 0], xs1 = xsq_g[prow + 1];
            const float xs2 = xsq_g[prow + 2], xs3 = xsq_g[prow + 3];
#pragma unroll
            for (int ct = 0; ct < 8; ++ct) {
                const unsigned short* cb = &c_lds[(ct * 16 + lr) * CPAD];
                const bf16x8 b0 = *reinterpret_cast<const bf16x8*>(cb + grp * 8);
                const bf16x8 b1 = *reinterpret_cast<const bf16x8*>(cb + 32 + grp * 8);
                f32x4 acc = {0.f, 0.f, 0.f, 0.f};
                acc = __builtin_amdgcn_mfma_f32_16x16x32_bf16(a0, b0, acc, 0, 0, 0);
                acc = __builtin_amdgcn_mfma_f32_16x16x32_bf16(a1, b1, acc, 0, 0, 0);
                const float cs = csq_lds[h * 128 + ct * 16 + lr];
                rm[q][0] = fminf(rm[q][0], __fadd_rn(fmaf(-2.0f, acc[0], xs0), cs));
                rm[q][1] = fminf(rm[q][1], __fadd_rn(fmaf(-2.0f, acc[1], xs1), cs));
                rm[q][2] = fminf(rm[q][2], __fadd_rn(fmaf(-2.0f, acc[2], xs2), cs));
                rm[q][3] = fminf(rm[q][3], __fadd_rn(fmaf(-2.0f, acc[3], xs3), cs));
            }
        }
    }

    // ---- reduce rm across the 16-lane groups ----
#pragma unroll
    for (int q = 0; q < 4; ++q) {
#pragma unroll
        for (int m = 1; m < 16; m <<= 1) {
            rm[q][0] = fminf(rm[q][0], __shfl_xor(rm[q][0], m, 64));
            rm[q][1] = fminf(rm[q][1], __shfl_xor(rm[q][1], m, 64));
            rm[q][2] = fminf(rm[q][2], __shfl_xor(rm[q][2], m, 64));
            rm[q][3] = fminf(rm[q][3], __shfl_xor(rm[q][3], m, 64));
        }
    }

    // ---- pass B: recompute (bitwise-identical) + push candidates ----
#pragma unroll
    for (int h = 0; h < 2; ++h) {
        __syncthreads();
        for (int idx = t; idx < 128 * 8; idx += 256) {
            const int row = idx >> 3, ch = idx & 7;
            *reinterpret_cast<bf16x8*>(&c_lds[row * CPAD + ch * 8]) =
                *reinterpret_cast<const bf16x8*>(cbf + (size_t)(h * 128 + row) * DIM + ch * 8);
        }
        __syncthreads();
#pragma unroll
        for (int q = 0; q < 4; ++q) {
            const int pbase = p0 + w * 64 + q * 16;
            const unsigned short* xb = xbf + (size_t)(pbase + lr) * DIM;
            const bf16x8 a0 = *reinterpret_cast<const bf16x8*>(xb + grp * 8);
            const bf16x8 a1 = *reinterpret_cast<const bf16x8*>(xb + 32 + grp * 8);
            const int prow = pbase + grp * 4;
            const float xs0 = xsq_g[prow + 0], xs1 = xsq_g[prow + 1];
            const float xs2 = xsq_g[prow + 2], xs3 = xsq_g[prow + 3];
            const float th0 = rm[q][0] + 2.0f * (0.00399f * sqrtf(xs0 * csqmax) + 0.02f);
            const float th1 = rm[q][1] + 2.0f * (0.00399f * sqrtf(xs1 * csqmax) + 0.02f);
            const float th2 = rm[q][2] + 2.0f * (0.00399f * sqrtf(xs2 * csqmax) + 0.02f);
            const float th3 = rm[q][3] + 2.0f * (0.00399f * sqrtf(xs3 * csqmax) + 0.02f);
            const int pidx0 = w * 64 + q * 16 + grp * 4;
#pragma unroll
            for (int ct = 0; ct < 8; ++ct) {
                const unsigned short* cb = &c_lds[(ct * 16 + lr) * CPAD];
                const bf16x8 b0 = *reinterpret_cast<const bf16x8*>(cb + grp * 8);
                const bf16x8 b1 = *reinterpret_cast<const bf16x8*>(cb + 32 + grp * 8);
                f32x4 acc = {0.f, 0.f, 0.f, 0.f};
                acc = __builtin_amdgcn_mfma_f32_16x16x32_bf16(a0, b0, acc, 0, 0, 0);
                acc = __builtin_amdgcn_mfma_f32_16x16x32_bf16(a1, b1, acc, 0, 0, 0);
                const int kcol = h * 128 + ct * 16 + lr;
                const float cs = csq_lds[kcol];
                const float d0 = __fadd_rn(fmaf(-2.0f, acc[0], xs0), cs);
                const float d1 = __fadd_rn(fmaf(-2.0f, acc[1], xs1), cs);
                const float d2 = __fadd_rn(fmaf(-2.0f, acc[2], xs2), cs);
                const float d3 = __fadd_rn(fmaf(-2.0f, acc[3], xs3), cs);
                if (d0 <= th0) { int s = atomicAdd(&ccnt[pidx0 + 0], 1); if (s < 8) cand[(pidx0 + 0) * 8 + s] = (short)kcol; }
                if (d1 <= th1) { int s = atomicAdd(&ccnt[pidx0 + 1], 1); if (s < 8) cand[(pidx0 + 1) * 8 + s] = (short)kcol; }
                if (d2 <= th2) { int s = atomicAdd(&ccnt[pidx0 + 2], 1); if (s < 8) cand[(pidx0 + 2) * 8 + s] = (short)kcol; }
                if (d3 <= th3) { int s = atomicAdd(&ccnt[pidx0 + 3], 1); if (s < 8) cand[(pidx0 + 3) * 8 + s] = (short)kcol; }
            }
        }
    }
    __syncthreads();

    // ---- eval: nc==1 -> candidate IS the exact argmin; else exact r4 chain ----
    const int i = p0 + t;
    const bool valid = (i < n);
    int lbl = 0;
    if (valid) {
        const int nc = ccnt[t];
        if (firstNan != 0x7fffffff) {
            lbl = firstNan;
        } else if (nc == 1) {
            lbl = (int)cand[t * 8];
        } else {
            const float xsqv = xsq_g[i];
            const float4* xrow = reinterpret_cast<const float4*>(x + (size_t)i * DIM);
            float bd = 3.4e38f;
            int bk = 0;
            const bool fullscan = (nc == 0) || (nc > 8);
            const int lim = fullscan ? KC : nc;
            for (int s = 0; s < lim; ++s) {
                const int k = fullscan ? s : (int)cand[t * 8 + s];
                const float4* crow = reinterpret_cast<const float4*>(c + (size_t)k * DIM);
                float acc = 0.0f;
#pragma unroll
                for (int db = 0; db < 16; ++db) {
                    const float4 a = xrow[db], b = crow[db];
                    acc = fmaf(a.x, b.x, acc); acc = fmaf(a.y, b.y, acc);
                    acc = fmaf(a.z, b.z, acc); acc = fmaf(a.w, b.w, acc);
                }
                const float dd = __fadd_rn(fmaf(-2.0f, acc, xsqv), csq_lds[k]);
                if (dd < bd) { bd = dd; bk = k; }
                else if (dd == bd && k < bk) bk = k;
            }
            lbl = bk;
        }
        labels[i] = (float)lbl;
    }
    __syncthreads();                 // all cand/ccnt reads done -> safe to reuse u_shm

    // ---- whist ballot (u_shm reused) ----
    int* whist = u_shm;
    for (int j = t; j < 4 * KC; j += 256) whist[j] = 0;
    __syncthreads();
    const int lane = t & 63, wv = t >> 6;
    unsigned long long same = __ballot(valid);
#pragma unroll
    for (int bit = 0; bit < 8; ++bit) {
        unsigned long long bb = __ballot((lbl >> bit) & 1);
        same &= ((lbl >> bit) & 1) ? bb : ~bb;
    }
    if (valid && lane == __builtin_ctzll(same))
        whist[wv * KC + lbl] = (int)__popcll(same);
    __syncthreads();
    if (t < KC)
        hist[(size_t)blockIdx.x * KC + t] =
            whist[t] + whist[KC + t] + whist[2 * KC + t] + whist[3 * KC + t];
}

// ---------------- fallback assign (r15-proven, passing) ----------------
__global__ __launch_bounds__(256) void assign_hist_k(
    const float* __restrict__ x, const float* __restrict__ c,
    const float* __restrict__ csq_g, const int* __restrict__ nan_g,
    float* __restrict__ labels, int* __restrict__ hist, int n)
{
    __shared__ int whist[4 * KC];
    const int t = threadIdx.x;
    for (int j = t; j < 4 * KC; j += 256) whist[j] = 0;

    const int i = blockIdx.x * 256 + t;
    const bool valid = (i < n);

    float xr[DIM];
    const float4* xv = reinterpret_cast<const float4*>(x + (size_t)(valid ? i : 0) * DIM);
#pragma unroll
    for (int j = 0; j < DIM / 4; ++j) {
        float4 v = xv[j];
        xr[4 * j + 0] = v.x; xr[4 * j + 1] = v.y;
        xr[4 * j + 2] = v.z; xr[4 * j + 3] = v.w;
    }
    const float xsq = np_pairwise_sq64(xr);
    const int firstNan = *nan_g;

    float best = __int_as_float(0x7f800000);
    int bk = 0;

#pragma unroll 1
    for (int k = 0; k < KC; ++k) {
        f32x16 h0, h1, h2, h3;
        float cs;
        const float* rp = c + (size_t)k * DIM;
        asm volatile("s_load_dwordx16 %0, %1, 0x0"  : "=s"(h0) : "s"(rp));
        asm volatile("s_load_dwordx16 %0, %1, 0x40" : "=s"(h1) : "s"(rp));
        asm volatile("s_load_dwordx16 %0, %1, 0x80" : "=s"(h2) : "s"(rp));
        asm volatile("s_load_dwordx16 %0, %1, 0xc0" : "=s"(h3) : "s"(rp));
        asm volatile("s_load_dword %0, %1, 0x0"     : "=s"(cs) : "s"(csq_g + k));
        asm volatile("s_waitcnt lgkmcnt(0)"
                     : "+s"(h0), "+s"(h1), "+s"(h2), "+s"(h3), "+s"(cs));
        __builtin_amdgcn_sched_barrier(0);

        float acc = 0.0f;
#pragma unroll
        for (int d = 0; d < 16; ++d) acc = fmaf(xr[d],      h0[d], acc);
#pragma unroll
        for (int d = 0; d < 16; ++d) acc = fmaf(xr[16 + d], h1[d], acc);
#pragma unroll
        for (int d = 0; d < 16; ++d) acc = fmaf(xr[32 + d], h2[d], acc);
#pragma unroll
        for (int d = 0; d < 16; ++d) acc = fmaf(xr[48 + d], h3[d], acc);

        const float dist = __fadd_rn(fmaf(-2.0f, acc, xsq), cs);
        if (dist < best) { best = dist; bk = k; }
    }

    int lbl = 0;
    if (valid) {
        lbl = (firstNan != 0x7fffffff) ? firstNan : bk;
        labels[i] = (float)lbl;
    }

    __syncthreads();
    const int lane = t & 63, w = t >> 6;
    unsigned long long same = __ballot(valid);
#pragma unroll
    for (int bit = 0; bit < 8; ++bit) {
        unsigned long long bb = __ballot((lbl >> bit) & 1);
        same &= ((lbl >> bit) & 1) ? bb : ~bb;
    }
    if (valid && lane == __builtin_ctzll(same))
        whist[w * KC + lbl] = (int)__popcll(same);
    __syncthreads();
    if (t < KC)
        hist[(size_t)blockIdx.x * KC + t] =
            whist[t] + whist[KC + t] + whist[2 * KC + t] + whist[3 * KC + t];
}

// ---------------- scan1: per-cluster exclusive prefix over blocks ----------------
__global__ __launch_bounds__(256) void scan1_k(
    int* __restrict__ hist, int nb, int* __restrict__ cnt)
{
    __shared__ int sbuf[256];
    const int k = blockIdx.x;
    const int t = threadIdx.x;
    const int epb = (nb + 255) / 256;
    const int b0 = t * epb;

    int s = 0;
    for (int u = 0; u < epb; ++u) {
        const int b = b0 + u;
        if (b < nb) s += hist[(size_t)b * KC + k];
    }
    sbuf[t] = s;
    __syncthreads();
    int incl = s;
#pragma unroll
    for (int d = 1; d < 256; d <<= 1) {
        const int v = (t >= d) ? sbuf[t - d] : 0;
        __syncthreads();
        incl += v;
        sbuf[t] = incl;
        __syncthreads();
    }
    int run = incl - s;
    for (int u = 0; u < epb; ++u) {
        const int b = b0 + u;
        if (b < nb) {
            const int v = hist[(size_t)b * KC + k];
            hist[(size_t)b * KC + k] = run;
            run += v;
        }
    }
    if (t == 255) cnt[k] = incl;
}

// ---------------- scan2: cluster bases (padded to 96 rows for 24-tile batches) ----------------
__global__ __launch_bounds__(256) void scan2_k(
    const int* __restrict__ cnt, int* __restrict__ base)
{
    __shared__ int sbuf[256];
    const int t = threadIdx.x;
    const int padded = ((cnt[t] + 95) / 96) * 96;
    sbuf[t] = padded;
    __syncthreads();
    int incl = padded;
#pragma unroll
    for (int d = 1; d < 256; d <<= 1) {
        const int v = (t >= d) ? sbuf[t - d] : 0;
        __syncthreads();
        incl += v;
        sbuf[t] = incl;
        __syncthreads();
    }
    base[t] = incl - padded;
}

// ---------------- scatter: stable counting-sort placement ----------------
__global__ __launch_bounds__(256) void scatter_k(
    const float* __restrict__ labels, const int* __restrict__ hist,
    const int* __restrict__ base, int* __restrict__ order, int n)
{
    __shared__ int whist[4 * KC];
    const int t = threadIdx.x;
    for (int j = t; j < 4 * KC; j += 256) whist[j] = 0;
    __syncthreads();

    const int i = blockIdx.x * 256 + t;
    const bool valid = (i < n);
    const int lbl = valid ? (int)labels[i] : 0;
    const int lane = t & 63, w = t >> 6;

    unsigned long long same = __ballot(valid);
#pragma unroll
    for (int bit = 0; bit < 8; ++bit) {
        unsigned long long bb = __ballot((lbl >> bit) & 1);
        same &= ((lbl >> bit) & 1) ? bb : ~bb;
    }
    const unsigned long long below = (1ull << lane) - 1ull;
    const int rank_wave = (int)__popcll(same & below);
    if (valid && lane == __builtin_ctzll(same))
        whist[w * KC + lbl] = (int)__popcll(same);
    __syncthreads();

    if (valid) {
        int off = rank_wave;
        for (int ww = 0; ww < w; ++ww) off += whist[ww * KC + lbl];
        const int pos = base[lbl] + hist[(size_t)blockIdx.x * KC + lbl] + off;
        order[pos] = i;
    }
}

// ---------------- permute2: tiled layout xs2[tile][d*4 + (r&3)] = x[order[r]][d] ----------------
// One wave per 4-row tile; LDS transpose; pads (order<0) -> zeros (exact no-ops in sum).
__global__ __launch_bounds__(256) void permute2_k(
    const float* __restrict__ x, const int* __restrict__ order,
    float* __restrict__ xs2)
{
    __shared__ float tile[4][4][65];   // [wave][row][dim(+pad)]
    const int t = threadIdx.x;
    const int w = t >> 6, l = t & 63;
    const int j = blockIdx.x * 4 + w;          // tile index
    const int g = l >> 4, m = l & 15;          // row-in-tile (16 lanes each), dim-quad

    const int idx = order[4 * j + g];          // broadcast within 16-lane group
    float4 v = make_float4(0.f, 0.f, 0.f, 0.f);
    if (idx >= 0) v = *reinterpret_cast<const float4*>(x + (size_t)idx * DIM + m * 4);
    tile[w][g][m * 4 + 0] = v.x;
    tile[w][g][m * 4 + 1] = v.y;
    tile[w][g][m * 4 + 2] = v.z;
    tile[w][g][m * 4 + 3] = v.w;
    // same-wave LDS RAW: compiler inserts lgkmcnt wait
    float4 o;
    o.x = tile[w][0][l]; o.y = tile[w][1][l];
    o.z = tile[w][2][l]; o.w = tile[w][3][l];
    *reinterpret_cast<float4*>(xs2 + (size_t)j * 256 + l * 4) = o;   // coalesced 1KB
}

// ---------------- sum6: 24-slot asm vmcnt pipeline; exact ascending f32 chain ----------------
// One wave per cluster. Lane = dim. Each dwordx4 = 4 consecutive rows of this dim
// (tiled layout). 24 loads in flight (96 rows); s_waitcnt vmcnt(23) -> oldest done.
// Chain order identical to proven sum2 (tiles ascending, x..w = rows 4t..4t+3).
#define SLOT_ISSUE(i) { asm volatile("global_load_dwordx4 %0, %1, off" \
                          : "=v"(A##i) : "v"(addr)); addr += 1024ull; }
#define SLOT_ADDS(i)  { acc = __fadd_rn(acc, A##i.x); acc = __fadd_rn(acc, A##i.y); \
                        acc = __fadd_rn(acc, A##i.z); acc = __fadd_rn(acc, A##i.w); }
#define SLOT_STEP(i)  { asm volatile("s_waitcnt vmcnt(23)" : "+v"(A##i)); \
                        __builtin_amdgcn_sched_barrier(0); SLOT_ADDS(i) SLOT_ISSUE(i) }
#define SLOT_DRAIN(i, cnt) { asm volatile("s_waitcnt vmcnt(" #cnt ")" : "+v"(A##i)); \
                        __builtin_amdgcn_sched_barrier(0); SLOT_ADDS(i) }

__global__ __launch_bounds__(64) void sum6_k(
    const float* __restrict__ xs2, const int* __restrict__ base,
    const int* __restrict__ cnt, float* __restrict__ c)
{
    const int k = blockIdx.x;
    const int lane = threadIdx.x;                 // = dim
    const int b0 = base[k];                       // multiple of 96
    const int ct = cnt[k];
    const int ctp = ((ct + 95) / 96) * 96;        // padded rows (zeros at tail)
    const int T = ctp >> 2;                       // tiles, multiple of 24

    float acc = 0.0f;
    if (T > 0) {
        unsigned long long addr =
            (unsigned long long)(const void*)(xs2 + (size_t)(b0 >> 2) * 256 + lane * 4);
        f32x4 A0, A1, A2, A3, A4, A5, A6, A7, A8, A9, A10, A11;
        f32x4 A12, A13, A14, A15, A16, A17, A18, A19, A20, A21, A22, A23;

        SLOT_ISSUE(0)  SLOT_ISSUE(1)  SLOT_ISSUE(2)  SLOT_ISSUE(3)
        SLOT_ISSUE(4)  SLOT_ISSUE(5)  SLOT_ISSUE(6)  SLOT_ISSUE(7)
        SLOT_ISSUE(8)  SLOT_ISSUE(9)  SLOT_ISSUE(10) SLOT_ISSUE(11)
        SLOT_ISSUE(12) SLOT_ISSUE(13) SLOT_ISSUE(14) SLOT_ISSUE(15)
        SLOT_ISSUE(16) SLOT_ISSUE(17) SLOT_ISSUE(18) SLOT_ISSUE(19)
        SLOT_ISSUE(20) SLOT_ISSUE(21) SLOT_ISSUE(22) SLOT_ISSUE(23)

        const int nsteps = T / 24 - 1;
        for (int s2 = 0; s2 < nsteps; ++s2) {
            SLOT_STEP(0)  SLOT_STEP(1)  SLOT_STEP(2)  SLOT_STEP(3)
            SLOT_STEP(4)  SLOT_STEP(5)  SLOT_STEP(6)  SLOT_STEP(7)
            SLOT_STEP(8)  SLOT_STEP(9)  SLOT_STEP(10) SLOT_STEP(11)
            SLOT_STEP(12) SLOT_STEP(13) SLOT_STEP(14) SLOT_STEP(15)
            SLOT_STEP(16) SLOT_STEP(17) SLOT_STEP(18) SLOT_STEP(19)
            SLOT_STEP(20) SLOT_STEP(21) SLOT_STEP(22) SLOT_STEP(23)
        }

        SLOT_DRAIN(0, 23)  SLOT_DRAIN(1, 22)  SLOT_DRAIN(2, 21)  SLOT_DRAIN(3, 20)
        SLOT_DRAIN(4, 19)  SLOT_DRAIN(5, 18)  SLOT_DRAIN(6, 17)  SLOT_DRAIN(7, 16)
        SLOT_DRAIN(8, 15)  SLOT_DRAIN(9, 14)  SLOT_DRAIN(10, 13) SLOT_DRAIN(11, 12)
        SLOT_DRAIN(12, 11) SLOT_DRAIN(13, 10) SLOT_DRAIN(14, 9)  SLOT_DRAIN(15, 8)
        SLOT_DRAIN(16, 7)  SLOT_DRAIN(17, 6)  SLOT_DRAIN(18, 5)  SLOT_DRAIN(19, 4)
        SLOT_DRAIN(20, 3)  SLOT_DRAIN(21, 2)  SLOT_DRAIN(22, 1)  SLOT_DRAIN(23, 0)
    }
    c[k * DIM + lane] = __fdiv_rn(acc, (float)ct);   // 0/0 -> NaN matches ref
}

// ---------------- fallback gather (used only if d_ws too small) ----------------
__global__ __launch_bounds__(64) void gather_k(
    const float* __restrict__ x, const int* __restrict__ order,
    const int* __restrict__ base, const int* __restrict__ cnt,
    float* __restrict__ c)
{
    const int k = blockIdx.x;
    const int lane = threadIdx.x;
    const int b0 = base[k];
    const int ct = cnt[k];
    float acc = 0.0f;
    int j = 0;
    for (; j + 32 <= ct; j += 32) {
        float v[32];
#pragma unroll
        for (int u = 0; u < 32; ++u)
            v[u] = x[(size_t)order[b0 + j + u] * DIM + lane];
#pragma unroll
        for (int u = 0; u < 32; ++u) acc = __fadd_rn(acc, v[u]);
    }
    for (; j < ct; ++j)
        acc = __fadd_rn(acc, x[(size_t)order[b0 + j] * DIM + lane]);
    c[k * DIM + lane] = __fdiv_rn(acc, (float)ct);
}

extern "C" void kernel_launch(void* const* d_in, const int* in_sizes, int n_in,
                              void* d_out, int out_size, void* d_ws, size_t ws_size,
                              hipStream_t stream)
{
    const float* x = (const float*)d_in[0];
    const int n = in_sizes[0] / DIM;          // 262144

    float* out_c = (float*)d_out;
    float* out_labels = out_c + KC * DIM;

    const int nb = (n + 255) / 256;           // 1024 blocks of 256 points
    const int nstride = n + KC * 96;          // 286720 (multiple of 16 rows)

    size_t off = 0;
    auto alloc = [&](size_t bytes) -> size_t {
        size_t o = off; off = (off + bytes + 255) & ~(size_t)255; return o;
    };
    char*  w        = (char*)d_ws;
    float* csq_g    = (float*)(w + alloc(KC * sizeof(float)));
    int*   nan_g    = (int*)(w + alloc(256));
    float* csqmax_g = (float*)(w + alloc(256));
    unsigned short* cbf_g = (unsigned short*)(w + alloc(KC * DIM * sizeof(unsigned short)));
    int*   hist  = (int*)(w + alloc((size_t)nb * KC * sizeof(int)));
    int*   base  = (int*)(w + alloc(KC * sizeof(int)));
    int*   cnt   = (int*)(w + alloc(KC * sizeof(int)));
    int*   order = (int*)(w + alloc((size_t)nstride * sizeof(int)));
    const size_t med_need = off;
    float* xs2   = (float*)(w + alloc((size_t)nstride * DIM * sizeof(float)));
    const size_t big_need = off;
    unsigned short* xbf = (unsigned short*)(w + alloc((size_t)n * DIM * sizeof(unsigned short)));
    float* xsq_g = (float*)(w + alloc((size_t)n * sizeof(float)));
    const size_t huge_need = off;

    const bool med  = (ws_size >= med_need);
    const bool big  = (ws_size >= big_need);
    const bool huge = (ws_size >= huge_need);

    init_k<<<(KC * DIM + 255) / 256, 256, 0, stream>>>(x, out_c);
    if (huge)
        xinit_k<<<nb, 256, 0, stream>>>(x, xbf, xsq_g, n);

    for (int it = 0; it < NITER; ++it) {
        if (huge) {
            csqg2_k<<<1, 256, 0, stream>>>(out_c, csq_g, nan_g, cbf_g, csqmax_g);
            assign_mfma_k<<<nb, 256, 0, stream>>>(x, xbf, xsq_g, out_c, cbf_g,
                                                  csq_g, csqmax_g, nan_g,
                                                  out_labels, hist, n);
        } else {
            csqg_k<<<1, 256, 0, stream>>>(out_c, csq_g, nan_g);
            assign_hist_k<<<nb, 256, 0, stream>>>(x, out_c, csq_g, nan_g,
                                                  out_labels, hist, n);
        }
        if (med) {
            scan1_k<<<KC, 256, 0, stream>>>(hist, nb, cnt);
            scan2_k<<<1, 256, 0, stream>>>(cnt, base);
            if (big) {
                (void)hipMemsetAsync(order, 0xFF, (size_t)nstride * sizeof(int), stream);
                scatter_k<<<nb, 256, 0, stream>>>(out_labels, hist, base, order, n);
                permute2_k<<<nstride / 16, 256, 0, stream>>>(x, order, xs2);
                sum6_k<<<KC, 64, 0, stream>>>(xs2, base, cnt, out_c);
            } else {
                scatter_k<<<nb, 256, 0, stream>>>(out_labels, hist, base, order, n);
                gather_k<<<KC, 64, 0, stream>>>(x, order, base, cnt, out_c);
            }
        }
    }
}